// Round 7
// baseline (88.020 us; speedup 1.0000x reference)
//
#include <hip/hip_runtime.h>

// QuantumKernelMethod: analytic collapse.
//   out[x,y] = M^2,  M = prod_i cos((x_i - y_i)/2)
//            = prod_i [cos(x_i/2)cos(y_i/2) + sin(x_i/2)sin(y_i/2)]
// (params provably unused: RZ phases / CNOT permutation are sample-
// independent and cancel in |<x|y>|^2.)
//
// Ladder: R1 100.8 -> R3 fused 89.4 -> R5 tan-factored+packed 83.0 ->
// R6 CPT=4+nt 87.2 (REGRESSED: 512 blocks = 2 waves/SIMD; nt suspect).
// R7: row records [tx0..9, Cx, pad] are WAVE-UNIFORM -> move them out of
// LDS (R5: 96 ds_read_b128/thread ~ 7.7us LDS pipe) into global + uniform
// s_load_dwordx4; tx feeds v_pk_fma directly as the SGPR operand (no
// splats). Inner loop: 3 s_load + ~24 VALU + 1 store per row. CPT=2,
// grid 1024 blocks, plain stores.

#define NS 4096   // samples per set
#define NW 10     // wires
#define ROWS 32   // rows per block
#define CPT 2     // columns per thread (one packed pair)

typedef float v2f __attribute__((ext_vector_type(2)));

static __device__ inline v2f splat2(float x) { v2f v; v.x = x; v.y = x; return v; }

// Build per-row records: rec[r] = {tan(x_rw/2) w=0..9, prod_w cos(x_rw/2), 0}
__global__ __launch_bounds__(256) void qkm_prep(
    const float* __restrict__ X, float* __restrict__ rec) {
    int r = blockIdx.x * 256 + threadIdx.x;      // 0..4095
    const float* xp = X + (size_t)r * NW;
    float t[NW];
    float cx = 1.0f;
#pragma unroll
    for (int w = 0; w < NW; ++w) {
        float s, c;
        __sincosf(0.5f * xp[w], &s, &c);
        // |cos(x/2)| >= ~4e-8 for representable x in [0,2pi]; guard anyway.
        float cs = (fabsf(c) < 1e-30f) ? copysignf(1e-30f, c) : c;
        t[w] = __fdividef(s, cs);
        cx *= cs;
    }
    float4* o = reinterpret_cast<float4*>(rec + (size_t)r * 12);  // 48B, 16B-aligned
    o[0] = make_float4(t[0], t[1], t[2], t[3]);
    o[1] = make_float4(t[4], t[5], t[6], t[7]);
    o[2] = make_float4(t[8], t[9], cx, 0.0f);
}

__global__ __launch_bounds__(256) void qkm_main(
    const float* __restrict__ rec, const float* __restrict__ Y,
    float* __restrict__ out) {
    const int col  = (blockIdx.x * 256 + threadIdx.x) * CPT;
    const int row0 = blockIdx.y * ROWS;

    // This thread's 2 columns: (cos,sin) of Y half-angles in packed regs.
    v2f cy[NW], sy[NW];
#pragma unroll
    for (int w = 0; w < NW; ++w) {
        float s0, c0, s1, c1;
        __sincosf(0.5f * Y[(size_t)col * NW + w], &s0, &c0);
        __sincosf(0.5f * Y[(size_t)(col + 1) * NW + w], &s1, &c1);
        v2f c; c.x = c0; c.y = c1;
        v2f s; s.x = s0; s.y = s1;
        cy[w] = c; sy[w] = s;
    }

#pragma unroll 4
    for (int r = 0; r < ROWS; ++r) {
        const int row = row0 + r;                 // block-uniform
        // Uniform address + __restrict__ => s_load_dwordx4 (SMEM pipe, K$).
        const float4* rp = reinterpret_cast<const float4*>(rec + (size_t)row * 12);
        float4 a0 = rp[0];                        // tx0..3
        float4 a1 = rp[1];                        // tx4..7
        float4 a2 = rp[2];                        // tx8, tx9, Cx, pad
        float tx[NW] = {a0.x, a0.y, a0.z, a0.w, a1.x, a1.y, a1.z, a1.w, a2.x, a2.y};
        v2f p = splat2(a2.z);                     // start from Cx (sgpr bcast)
#pragma unroll
        for (int w = 0; w < NW; ++w)
            p = p * (cy[w] + tx[w] * sy[w]);      // v_pk_fma (SGPR op) + v_pk_mul
        v2f o = p * p;
        *reinterpret_cast<v2f*>(out + (size_t)row * NS + col) = o;
    }
}

extern "C" void kernel_launch(void* const* d_in, const int* in_sizes, int n_in,
                              void* d_out, int out_size, void* d_ws, size_t ws_size,
                              hipStream_t stream) {
    const float* X = (const float*)d_in[0];   // (4096, 10)
    const float* Y = (const float*)d_in[1];   // (4096, 10)
    // d_in[2] = params (4,10): unused (phases cancel in |<x|y>|^2).
    float* out = (float*)d_out;               // (4096, 4096) fp32
    float* rec = (float*)d_ws;                // 4096 x 12 floats = 192 KB

    qkm_prep<<<NS / 256, 256, 0, stream>>>(X, rec);

    dim3 grid(NS / (256 * CPT), NS / ROWS);   // (8, 128) = 1024 blocks
    qkm_main<<<grid, 256, 0, stream>>>(rec, Y, out);
}

// Round 8
// 81.090 us; speedup vs baseline: 1.0855x; 1.0855x over previous
//
#include <hip/hip_runtime.h>

// QuantumKernelMethod: analytic collapse.
//   out[x,y] = M^2,  M = prod_i cos((x_i - y_i)/2)
//            = prod_i [cos(x_i/2)cos(y_i/2) + sin(x_i/2)sin(y_i/2)]
// (params provably unused: RZ phases / CNOT permutation are sample-
// independent and cancel in |<x|y>|^2.)
//
// Ladder: R1 100.8 -> R3 fused 89.4 -> R5 tan+packed CPT=2 83.0 (best) ->
// R6 CPT=4+nt+512blk 87.2 -> R7 two-kernel s_load 88.0 (both regressed).
// R8: CLEAN CPT=4 test — isolate it from R6's confounds: ROWS=16 keeps
// grid at 1024 blocks (same TLP as R5), plain b128 stores (no nt), no
// launch-bounds VGPR cap (R2 lesson). Halves LDS record reads and store
// insts per element vs R5.

#define NS 4096   // samples per set
#define NW 10     // wires
#define ROWS 16   // rows per block
#define CPT 4     // columns per thread (two packed pairs, one b128 store)

typedef float v2f __attribute__((ext_vector_type(2)));
typedef float v4f __attribute__((ext_vector_type(4)));

static __device__ inline v2f splat2(float x) { v2f v; v.x = x; v.y = x; return v; }

__global__ __launch_bounds__(256) void qkm_fused(
    const float* __restrict__ X, const float* __restrict__ Y,
    float* __restrict__ out) {
    __shared__ float xrow[ROWS][12];   // per row: tx[0..9], Cx, pad (48 B)
    __shared__ float cxa[ROWS][NW];    // staging for the Cx product reduce

    const int col  = (blockIdx.x * 256 + threadIdx.x) * CPT;
    const int row0 = blockIdx.y * ROWS;

    // Stage per-(row,wire): tan(x/2) and cos(x/2). ROWS*NW=160 <= 256, but
    // keep the strided form (R4 lesson) — it runs exactly once per thread.
    for (int t = threadIdx.x; t < ROWS * NW; t += 256) {
        int r = t / NW;
        int w = t - r * NW;
        float s, c;
        __sincosf(0.5f * X[(row0 + r) * NW + w], &s, &c);
        // |cos(x/2)| >= ~4e-8 for representable x in [0,2pi]; guard anyway.
        float cs = (fabsf(c) < 1e-30f) ? copysignf(1e-30f, c) : c;
        xrow[r][w] = __fdividef(s, cs);   // tx = tan(x/2)
        cxa[r][w]  = cs;
    }

    // This thread's 4 columns: (cos,sin) of Y half-angles, two packed pairs.
    v2f cy[NW][2], sy[NW][2];
#pragma unroll
    for (int j = 0; j < 2; ++j) {
#pragma unroll
        for (int w = 0; w < NW; ++w) {
            float s0, c0, s1, c1;
            __sincosf(0.5f * Y[(size_t)(col + 2 * j) * NW + w], &s0, &c0);
            __sincosf(0.5f * Y[(size_t)(col + 2 * j + 1) * NW + w], &s1, &c1);
            v2f c; c.x = c0; c.y = c1;
            v2f s; s.x = s0; s.y = s1;
            cy[w][j] = c; sy[w][j] = s;
        }
    }

    __syncthreads();
    if (threadIdx.x < ROWS) {                 // Cx = prod_i cos(x_i/2)
        int r = threadIdx.x;
        float p = cxa[r][0];
#pragma unroll
        for (int w = 1; w < NW; ++w) p *= cxa[r][w];
        xrow[r][NW] = p;
    }
    __syncthreads();

#pragma unroll 2
    for (int r = 0; r < ROWS; ++r) {
        float a[12];                          // tx[0..9], Cx  (3x ds_read_b128)
        *reinterpret_cast<float4*>(&a[0]) = *reinterpret_cast<const float4*>(&xrow[r][0]);
        *reinterpret_cast<float4*>(&a[4]) = *reinterpret_cast<const float4*>(&xrow[r][4]);
        *reinterpret_cast<float4*>(&a[8]) = *reinterpret_cast<const float4*>(&xrow[r][8]);
        v2f p0 = splat2(a[NW]);               // start from Cx
        v2f p1 = p0;
#pragma unroll
        for (int w = 0; w < NW; ++w) {
            const v2f t = splat2(a[w]);
            p0 = p0 * (cy[w][0] + t * sy[w][0]);   // v_pk_fma + v_pk_mul
            p1 = p1 * (cy[w][1] + t * sy[w][1]);
        }
        v4f o;
        o.x = p0.x * p0.x; o.y = p0.y * p0.y;
        o.z = p1.x * p1.x; o.w = p1.y * p1.y;
        *reinterpret_cast<v4f*>(out + (size_t)(row0 + r) * NS + col) = o;
    }
}

extern "C" void kernel_launch(void* const* d_in, const int* in_sizes, int n_in,
                              void* d_out, int out_size, void* d_ws, size_t ws_size,
                              hipStream_t stream) {
    const float* X = (const float*)d_in[0];   // (4096, 10)
    const float* Y = (const float*)d_in[1];   // (4096, 10)
    // d_in[2] = params (4,10): unused (phases cancel in |<x|y>|^2).
    float* out = (float*)d_out;               // (4096, 4096) fp32

    dim3 grid(NS / (256 * CPT), NS / ROWS);   // (4, 256) = 1024 blocks
    qkm_fused<<<grid, 256, 0, stream>>>(X, Y, out);
}